// Round 2
// baseline (546.396 us; speedup 1.0000x reference)
//
#include <hip/hip_runtime.h>
#include <hip/hip_bf16.h>

#define NB 8
#define N1 2048
#define N2 1152
#define KD 1024
#define BM 256
#define BN 144
#define BK 32
#define BNP 145  // padded epilogue stride (odd -> spreads banks)

typedef __attribute__((ext_vector_type(8))) short bf16x8;
typedef __attribute__((ext_vector_type(4))) float f32x4;

__device__ __forceinline__ unsigned short f2bf_rne(float f) {
  union { float f; unsigned u; } c; c.f = f;
  unsigned u = c.u;
  u += 0x7FFFu + ((u >> 16) & 1u);
  return (unsigned short)(u >> 16);
}

// One WAVE per row: convert fp32->bf16 (RNE) + fp32 row squared norm.
// No __syncthreads, 4x float4 per lane for MLP.
__global__ __launch_bounds__(256) void convert_kernel(
    const float* __restrict__ x1, const float* __restrict__ x2,
    unsigned short* __restrict__ x1b, unsigned short* __restrict__ x2b,
    float* __restrict__ sq1, float* __restrict__ sq2) {
  int wave = threadIdx.x >> 6, lane = threadIdx.x & 63;
  int row = blockIdx.x * 4 + wave;
  const float* src;
  unsigned short* dst;
  float* sqp;
  if (row < NB * N1) {
    src = x1 + (size_t)row * KD;
    dst = x1b + (size_t)row * KD;
    sqp = sq1 + row;
  } else {
    int r = row - NB * N1;
    src = x2 + (size_t)r * KD;
    dst = x2b + (size_t)r * KD;
    sqp = sq2 + r;
  }
  const float4* s4 = (const float4*)src;
  ushort4* d4 = (ushort4*)dst;
  float s = 0.f;
#pragma unroll
  for (int i = 0; i < 4; ++i) {
    float4 v = s4[i * 64 + lane];
    ushort4 o;
    o.x = f2bf_rne(v.x);
    o.y = f2bf_rne(v.y);
    o.z = f2bf_rne(v.z);
    o.w = f2bf_rne(v.w);
    d4[i * 64 + lane] = o;
    s += v.x * v.x + v.y * v.y + v.z * v.z + v.w * v.w;
  }
#pragma unroll
  for (int off = 32; off > 0; off >>= 1) s += __shfl_down(s, off);
  if (lane == 0) *sqp = s;
}

__device__ __forceinline__ void async_copy16(const void* g, void* l) {
  __builtin_amdgcn_global_load_lds(
      (const __attribute__((address_space(1))) unsigned int*)g,
      (__attribute__((address_space(3))) unsigned int*)l, 16, 0, 0);
}

// Fused distance + group-min(9) + mean.
// Block tile 256(M) x 144(N); 4 waves, wave w owns rows [w*64, w*64+64):
// 4 M-tiles x 9 N-tiles of 16x16x32 MFMA = 36 acc tiles (144 VGPR).
// LDS staging: A 16 chunks @0, B 9 chunks @16384 (1 KB chunks = 16 rows x 32 bf16).
// XOR swizzle within chunk: slot t holds col8 = t ^ ((row>>1)&3) -> any aligned
// 8-lane group of a b128 fragment read covers all 32 banks (hand-verified).
__global__ __launch_bounds__(256) void dist_kernel(
    const unsigned short* __restrict__ x1b, const unsigned short* __restrict__ x2b,
    const float* __restrict__ sq1, const float* __restrict__ sq2,
    float* __restrict__ out) {
  __shared__ __align__(16) char smem[64 * BNP * 4];  // 37120 B (union: staging 25600 B)

  const int tid = threadIdx.x;
  const int wave = tid >> 6, lane = tid & 63;
  const int bm = blockIdx.x, bn = blockIdx.y, b = blockIdx.z;

  const unsigned short* Ag = x1b + ((size_t)b * N1 + bm * BM) * KD;
  const unsigned short* Bg = x2b + ((size_t)b * N2 + bn * BN) * KD;

  // staging lane decomposition: lane -> (row lr in chunk, swizzled slot)
  const int lr = lane >> 2;                       // 0..15
  const int c8 = (lane & 3) ^ ((lr >> 1) & 3);    // swizzled col8 this lane fetches
  const int gcol = c8 * 8;                        // element offset in K-slab

  const int quad = lane >> 4;  // 0..3
  const int fr = lane & 15;    // fragment row (A) / row (B) / D col
  const int sw = (fr >> 1) & 3;
  const int tq16 = (quad ^ sw) * 16;  // swizzled 16B-slot byte offset

  f32x4 acc[4][9];
#pragma unroll
  for (int i = 0; i < 4; ++i)
#pragma unroll
    for (int j = 0; j < 9; ++j) {
      f32x4 z = {0.f, 0.f, 0.f, 0.f};
      acc[i][j] = z;
    }

  for (int k0 = 0; k0 < KD; k0 += BK) {
    // 25 chunks: 0..15 = A (256 rows), 16..24 = B (144 rows); chunk j at smem + j*1024
#pragma unroll 1
    for (int j = wave; j < 25; j += 4) {
      const unsigned short* g;
      if (j < 16)
        g = Ag + (size_t)(j * 16 + lr) * KD + k0 + gcol;
      else
        g = Bg + (size_t)((j - 16) * 16 + lr) * KD + k0 + gcol;
      async_copy16(g, smem + j * 1024 + lane * 16);
    }
    __syncthreads();

    bf16x8 a[4];
#pragma unroll
    for (int tm = 0; tm < 4; ++tm)
      a[tm] = *(const bf16x8*)(smem + (wave * 4 + tm) * 1024 + fr * 64 + tq16);
#pragma unroll
    for (int tn = 0; tn < 9; ++tn) {
      bf16x8 bF = *(const bf16x8*)(smem + 16384 + tn * 1024 + fr * 64 + tq16);
#pragma unroll
      for (int tm = 0; tm < 4; ++tm)
        acc[tm][tn] = __builtin_amdgcn_mfma_f32_16x16x32_bf16(a[tm], bF, acc[tm][tn], 0, 0, 0);
    }
    __syncthreads();
  }

  // ---- epilogue: d = sq1 + sq2 - 2*cross, min over 9-col groups, sum ----
  float s2[9];
#pragma unroll
  for (int tn = 0; tn < 9; ++tn)
    s2[tn] = sq2[(size_t)b * N2 + bn * BN + tn * 16 + fr];

  float s1v[4][4];
#pragma unroll
  for (int tm = 0; tm < 4; ++tm)
#pragma unroll
    for (int r = 0; r < 4; ++r)
      s1v[tm][r] = sq1[(size_t)b * N1 + bm * BM + wave * 64 + tm * 16 + quad * 4 + r];

  float* eps = (float*)smem;
  float local = 0.f;
#pragma unroll 1
  for (int tm = 0; tm < 4; ++tm) {
    __syncthreads();  // previous chunk / K-loop LDS fully consumed
    // D layout (16x16x32): col = lane&15 (x2 row), row = quad*4 + reg (x1 row)
    // chunk row = wave*16 + quad*4 + r  (64 rows, one 16-row band per wave)
#pragma unroll
    for (int tn = 0; tn < 9; ++tn)
#pragma unroll
      for (int r = 0; r < 4; ++r)
        eps[(wave * 16 + quad * 4 + r) * BNP + tn * 16 + fr] =
            s1v[tm][r] + s2[tn] - 2.0f * acc[tm][tn][r];
    __syncthreads();
    // 64 rows x 16 groups = 1024 groups, 4 per thread
#pragma unroll
    for (int q = 0; q < 4; ++q) {
      int g = tid + q * 256;
      int row = g >> 4, grp = g & 15;
      const float* p = eps + row * BNP + grp * 9;
      float mn = p[0];
#pragma unroll
      for (int jj = 1; jj < 9; ++jj) mn = fminf(mn, p[jj]);
      local += mn;
    }
  }

#pragma unroll
  for (int off = 32; off > 0; off >>= 1) local += __shfl_down(local, off);
  __syncthreads();
  if (lane == 0) eps[wave] = local;
  __syncthreads();
  if (tid == 0) {
    float s = eps[0] + eps[1] + eps[2] + eps[3];
    // total group count = 8 * 2048 * 1152 / 9 = 2097152
    atomicAdd(out, s * (1.0f / 2097152.0f));
  }
}

extern "C" void kernel_launch(void* const* d_in, const int* in_sizes, int n_in,
                              void* d_out, int out_size, void* d_ws, size_t ws_size,
                              hipStream_t stream) {
  const float* x1 = (const float*)d_in[0];
  const float* x2 = (const float*)d_in[1];
  char* ws = (char*)d_ws;
  const size_t x1b_bytes = (size_t)NB * N1 * KD * 2;  // 33554432
  const size_t x2b_bytes = (size_t)NB * N2 * KD * 2;  // 18874368
  unsigned short* x1b = (unsigned short*)ws;
  unsigned short* x2b = (unsigned short*)(ws + x1b_bytes);
  float* sq1 = (float*)(ws + x1b_bytes + x2b_bytes);
  float* sq2 = (float*)(ws + x1b_bytes + x2b_bytes + (size_t)NB * N1 * 4);

  hipMemsetAsync(d_out, 0, sizeof(float), stream);
  convert_kernel<<<NB * (N1 + N2) / 4, 256, 0, stream>>>(x1, x2, x1b, x2b, sq1, sq2);
  dist_kernel<<<dim3(N1 / BM, N2 / BN, NB), 256, 0, stream>>>(x1b, x2b, sq1, sq2,
                                                              (float*)d_out);
}

// Round 3
// 335.802 us; speedup vs baseline: 1.6271x; 1.6271x over previous
//
#include <hip/hip_runtime.h>
#include <hip/hip_bf16.h>

#define NB 8
#define N1 2048
#define N2 1152
#define KD 1024
#define BM 128
#define BN 144
#define BNP 145  // padded epilogue stride

typedef __attribute__((ext_vector_type(4))) float f32x4;
typedef __attribute__((ext_vector_type(4))) int i32x4;

union Frag16 {
  i32x4 v;
  long long ll[2];
};

__device__ __forceinline__ unsigned pack4_fp8(float4 v) {
  int t = __builtin_amdgcn_cvt_pk_fp8_f32(v.x, v.y, 0, false);
  t = __builtin_amdgcn_cvt_pk_fp8_f32(v.z, v.w, t, true);
  return (unsigned)t;
}

// One WAVE per row: fp32 -> fp8 e4m3 with k-block permutation + fp32 row norm.
// Output row layout (per 64-value k-block): 16B group q holds k = [q*8..q*8+7] ++
// [32+q*8..32+q*8+7], so one b128 LDS read = both k-half MFMA fragments.
__global__ __launch_bounds__(256) void convert_kernel(
    const float* __restrict__ x1, const float* __restrict__ x2,
    unsigned char* __restrict__ x1q, unsigned char* __restrict__ x2q,
    float* __restrict__ sq1, float* __restrict__ sq2) {
  int wave = threadIdx.x >> 6, lane = threadIdx.x & 63;
  int row = blockIdx.x * 4 + wave;
  const float* src;
  unsigned char* dst;
  float* sqp;
  if (row < NB * N1) {
    src = x1 + (size_t)row * KD;
    dst = x1q + (size_t)row * KD;
    sqp = sq1 + row;
  } else {
    int r = row - NB * N1;
    src = x2 + (size_t)r * KD;
    dst = x2q + (size_t)r * KD;
    sqp = sq2 + r;
  }
  const float4* s4 = (const float4*)src;
  int blk = lane >> 2, q = lane & 3;      // k-block 0..15, group 0..3
  int f1 = blk * 16 + q * 2;              // float4 idx of k = blk*64 + q*8
  int f2 = f1 + 8;                        // float4 idx of k = blk*64 + 32 + q*8
  float4 v0 = s4[f1], v1 = s4[f1 + 1], v2 = s4[f2], v3 = s4[f2 + 1];
  uint4 o;
  o.x = pack4_fp8(v0);
  o.y = pack4_fp8(v1);
  o.z = pack4_fp8(v2);
  o.w = pack4_fp8(v3);
  ((uint4*)dst)[lane] = o;  // byte offset lane*16
  float s = v0.x * v0.x + v0.y * v0.y + v0.z * v0.z + v0.w * v0.w +
            v1.x * v1.x + v1.y * v1.y + v1.z * v1.z + v1.w * v1.w +
            v2.x * v2.x + v2.y * v2.y + v2.z * v2.z + v2.w * v2.w +
            v3.x * v3.x + v3.y * v3.y + v3.z * v3.z + v3.w * v3.w;
#pragma unroll
  for (int off = 32; off > 0; off >>= 1) s += __shfl_down(s, off);
  if (lane == 0) *sqp = s;
}

__device__ __forceinline__ void async_copy16(const void* g, void* l) {
  __builtin_amdgcn_global_load_lds(
      (const __attribute__((address_space(1))) unsigned int*)g,
      (__attribute__((address_space(3))) unsigned int*)l, 16, 0, 0);
}

// Fused fp8 distance + group-min(9) + mean.
// Block tile 128(M) x 144(N), 4 waves, wave owns 32 rows: 2x9 acc tiles (72 VGPR
// of f32 acc — the R1-proven no-spill shape). K-step 64 (fp8): 16 iters.
// LDS chunks of 1 KB = 16 rows x 64 fp8, XOR-swizzled (slot ^ (row>>1)&3).
__global__ __launch_bounds__(256) void dist_kernel(
    const unsigned char* __restrict__ x1q, const unsigned char* __restrict__ x2q,
    const float* __restrict__ sq1, const float* __restrict__ sq2,
    float* __restrict__ out) {
  __shared__ __align__(16) char smem[64 * BNP * 4];  // 37120 B; staging uses 17408 B

  const int tid = threadIdx.x;
  const int wave = tid >> 6, lane = tid & 63;
  const int bm = blockIdx.x, bn = blockIdx.y, b = blockIdx.z;

  const unsigned char* Ag = x1q + ((size_t)b * N1 + bm * BM) * KD;
  const unsigned char* Bg = x2q + ((size_t)b * N2 + bn * BN) * KD;

  // staging: lane -> (row lr, 16B slot s), fetch swizzled global group
  const int lr = lane >> 2, sl = lane & 3;
  const int goff = (sl ^ ((lr >> 1) & 3)) * 16;

  // fragments: lane (fr, quad) reads swizzled slot -> global 16B group `quad`
  const int quad = lane >> 4, fr = lane & 15;
  const int fslot = (fr * 4 + (quad ^ ((fr >> 1) & 3))) * 16;

  f32x4 acc[2][9];
#pragma unroll
  for (int i = 0; i < 2; ++i)
#pragma unroll
    for (int j = 0; j < 9; ++j) {
      f32x4 z = {0.f, 0.f, 0.f, 0.f};
      acc[i][j] = z;
    }

  for (int k0 = 0; k0 < KD; k0 += 64) {
    // 17 chunks: 0..7 = A (128 rows), 8..16 = B (144 rows)
#pragma unroll 1
    for (int j = wave; j < 17; j += 4) {
      const unsigned char* g;
      if (j < 8)
        g = Ag + (size_t)(j * 16 + lr) * KD + k0 + goff;
      else
        g = Bg + (size_t)((j - 8) * 16 + lr) * KD + k0 + goff;
      async_copy16(g, smem + j * 1024 + lane * 16);
    }
    __syncthreads();

    Frag16 a0, a1;
    a0.v = *(const i32x4*)(smem + (wave * 2 + 0) * 1024 + fslot);
    a1.v = *(const i32x4*)(smem + (wave * 2 + 1) * 1024 + fslot);
#pragma unroll
    for (int tn = 0; tn < 9; ++tn) {
      Frag16 bf;
      bf.v = *(const i32x4*)(smem + 8192 + tn * 1024 + fslot);
      acc[0][tn] = __builtin_amdgcn_mfma_f32_16x16x32_fp8_fp8(a0.ll[0], bf.ll[0], acc[0][tn], 0, 0, 0);
      acc[0][tn] = __builtin_amdgcn_mfma_f32_16x16x32_fp8_fp8(a0.ll[1], bf.ll[1], acc[0][tn], 0, 0, 0);
      acc[1][tn] = __builtin_amdgcn_mfma_f32_16x16x32_fp8_fp8(a1.ll[0], bf.ll[0], acc[1][tn], 0, 0, 0);
      acc[1][tn] = __builtin_amdgcn_mfma_f32_16x16x32_fp8_fp8(a1.ll[1], bf.ll[1], acc[1][tn], 0, 0, 0);
    }
    __syncthreads();
  }

  // ---- epilogue: d = sq1 + sq2 - 2*cross, min over 9-col groups, sum ----
  float s2[9];
#pragma unroll
  for (int tn = 0; tn < 9; ++tn)
    s2[tn] = sq2[(size_t)b * N2 + bn * BN + tn * 16 + fr];

  float s1v[2][4];
#pragma unroll
  for (int tm = 0; tm < 2; ++tm)
#pragma unroll
    for (int r = 0; r < 4; ++r)
      s1v[tm][r] = sq1[(size_t)b * N1 + bm * BM + wave * 32 + tm * 16 + quad * 4 + r];

  float* eps = (float*)smem;
  float local = 0.f;
#pragma unroll 1
  for (int tm = 0; tm < 2; ++tm) {
    __syncthreads();  // previous chunk / K-loop LDS fully consumed
    // D layout (16x16x32): col = lane&15 (x2 row), row = quad*4 + reg (x1 row)
#pragma unroll
    for (int tn = 0; tn < 9; ++tn)
#pragma unroll
      for (int r = 0; r < 4; ++r)
        eps[(wave * 16 + quad * 4 + r) * BNP + tn * 16 + fr] =
            s1v[tm][r] + s2[tn] - 2.0f * acc[tm][tn][r];
    __syncthreads();
    // 64 rows x 16 groups = 1024 groups, 4 per thread
#pragma unroll
    for (int qq = 0; qq < 4; ++qq) {
      int g = tid + qq * 256;
      int row = g >> 4, grp = g & 15;
      const float* p = eps + row * BNP + grp * 9;
      float mn = p[0];
#pragma unroll
      for (int jj = 1; jj < 9; ++jj) mn = fminf(mn, p[jj]);
      local += mn;
    }
  }

#pragma unroll
  for (int off = 32; off > 0; off >>= 1) local += __shfl_down(local, off);
  __syncthreads();
  if (lane == 0) eps[wave] = local;
  __syncthreads();
  if (tid == 0) {
    float s = eps[0] + eps[1] + eps[2] + eps[3];
    // total group count = 8 * 2048 * 1152 / 9 = 2097152
    atomicAdd(out, s * (1.0f / 2097152.0f));
  }
}

extern "C" void kernel_launch(void* const* d_in, const int* in_sizes, int n_in,
                              void* d_out, int out_size, void* d_ws, size_t ws_size,
                              hipStream_t stream) {
  const float* x1 = (const float*)d_in[0];
  const float* x2 = (const float*)d_in[1];
  char* ws = (char*)d_ws;
  const size_t x1q_bytes = (size_t)NB * N1 * KD;  // 16777216
  const size_t x2q_bytes = (size_t)NB * N2 * KD;  // 9437184
  unsigned char* x1q = (unsigned char*)ws;
  unsigned char* x2q = (unsigned char*)(ws + x1q_bytes);
  float* sq1 = (float*)(ws + x1q_bytes + x2q_bytes);
  float* sq2 = (float*)(ws + x1q_bytes + x2q_bytes + (size_t)NB * N1 * 4);

  hipMemsetAsync(d_out, 0, sizeof(float), stream);
  convert_kernel<<<NB * (N1 + N2) / 4, 256, 0, stream>>>(x1, x2, x1q, x2q, sq1, sq2);
  dist_kernel<<<dim3(N1 / BM, N2 / BN, NB), 256, 0, stream>>>(x1q, x2q, sq1, sq2,
                                                              (float*)d_out);
}